// Round 16
// baseline (108.298 us; speedup 1.0000x reference)
//
#include <hip/hip_runtime.h>

// AttentionLayer: out = softmax(Q @ V^T) @ V ; B=4, SQ=SKV=4096, D=64, fp32.
//
// R15: TWO dispatches. R13's attn (44.5us; transposed S^T=V·Q^T, K=16 PV,
// per-lane softmax, dbuf LDS 32KB, 1 barrier/iter, XOR-swizzled tiles,
// 98K conflicts) now stages DIRECTLY from fp32 V: loads 4x float4/thread,
// converts (RNE), writes plain tile (2 b128, chunk c -> c^(r&7)) and
// kv-permuted transposed tile (16 ds_write_b16, same math as old prep).
// Kills the prep kernel (~15us dispatch overhead + ~5us work). V fp32 is
// 4 MB total -> L2-resident; 4x logical re-read costs ~7us of L2 BW.
// R12/R14 lessons: no __threadfence in hot loops (L2 writeback storm),
// no hipLaunchCooperativeKernel (silently incompatible with graph capture
// -> output never written). Three->two dispatches is the legal limit.

#define NB   4
#define SQ   4096
#define SKV  4096
#define DH   64
#define L2E  1.44269504088896340736f

typedef _Float16 half8 __attribute__((ext_vector_type(8)));
typedef _Float16 half4 __attribute__((ext_vector_type(4)));
typedef _Float16 half2v __attribute__((ext_vector_type(2)));
typedef float f32x4 __attribute__((ext_vector_type(4)));
typedef unsigned short u16;

#define MFMA16(a, b, c) __builtin_amdgcn_mfma_f32_16x16x16f16((a), (b), (c), 0, 0, 0)
#define MFMA32(a, b, c) __builtin_amdgcn_mfma_f32_16x16x32_f16((a), (b), (c), 0, 0, 0)

__device__ __forceinline__ u16 f2h(float f) {
  _Float16 h = (_Float16)f;
  return __builtin_bit_cast(u16, h);
}
__device__ __forceinline__ half2v pkrtz(float a, float b) {
  return __builtin_bit_cast(half2v, __builtin_amdgcn_cvt_pkrtz(a, b));
}

// ---------------------------------------------------------------- attn ----
// grid NB*64*S blocks, 256 threads = 4 waves * 16 q-cols each (64 q/block).
__global__ __launch_bounds__(256, 4) void attn_kernel(
    const float* __restrict__ Q,
    const float* __restrict__ V,
    u16* __restrict__ po,    // [NB*64*S][64 q][64 d] fp16 unnormalized O
    float* __restrict__ pm,  // [NB*64*S][64] running max (log2 domain)
    float* __restrict__ pl,  // [NB*64*S][64] running sum
    int S, int kvLen) {
  __shared__ __align__(16) u16 lds[2][2][4096];  // [buf][0=V,1=VT], 32 KB

  int blk  = blockIdx.x;
  int tile = blk / S;          // b*64 + qtile
  int s    = blk - tile * S;
  int b    = tile >> 6;
  int q0   = (tile & 63) << 6;
  int kv0  = s * kvLen;
  int t    = threadIdx.x;
  int wave = t >> 6;
  int lane = t & 63;
  int col  = lane & 15;
  int quad = lane >> 4;
  int qw   = q0 + (wave << 4);
  int c7   = col & 15 & 7;

  const float* gV = V + (size_t)(b * SKV) * DH;

  // staging geometry: row r = t>>2 (0..63), d-chunk dc = (t&3)*16
  int sr = t >> 2;
  int sdc = (t & 3) << 4;
  int sk = sr & 7;                     // plain-tile XOR swizzle key
  // transposed-write constants (element (d=sdc+i, kv=sr)):
  //   kc2=sr>>5, g=(sr>>4)&1, qd=(sr>>2)&3, lo=sr&3; H=(kc2<<2)|qd
  //   off_i = ((H ^ (i&7))<<3) + (g<<2) + lo   [since sdc&7 == 0]
  int sH   = (((sr >> 5) << 2) | ((sr >> 2) & 3));
  int srem = (((sr >> 4) & 1) << 2) + (sr & 3);

  // conversion + dual-layout LDS write of one staged row-chunk
  auto stage_write = [&](u16* dv, u16* dvt, const float4 f[4]) {
    u16 h[16];
#pragma unroll
    for (int i = 0; i < 4; ++i) {
      h[i * 4 + 0] = f2h(f[i].x); h[i * 4 + 1] = f2h(f[i].y);
      h[i * 4 + 2] = f2h(f[i].z); h[i * 4 + 3] = f2h(f[i].w);
    }
    // plain tile [kv][d]: two b128 chunk writes, phys chunk = c ^ (sr&7)
    int c0 = sdc >> 3;
    *(uint4*)(dv + (sr << 6) + (((c0)     ^ sk) << 3)) = *(const uint4*)(h);
    *(uint4*)(dv + (sr << 6) + (((c0 + 1) ^ sk) << 3)) = *(const uint4*)(h + 8);
    // transposed tile [d][kv-permuted]: 16 scalar writes (2-way banks)
#pragma unroll
    for (int i = 0; i < 16; ++i)
      dvt[((sdc + i) << 6) + ((sH ^ (i & 7)) << 3) + srem] = h[i];
  };

  // ---- Q fragment as B-operand (n=col=q, k=quad*8+j), log2e folded
  half8 qf[2];
#pragma unroll
  for (int kc = 0; kc < 2; ++kc) {
    const float* qp = Q + ((size_t)(b * SQ) + qw + col) * DH + kc * 32 + (quad << 3);
    float4 a0 = *(const float4*)qp;
    float4 a1 = *(const float4*)(qp + 4);
    half8 hq;
    hq[0] = (_Float16)(a0.x * L2E); hq[1] = (_Float16)(a0.y * L2E);
    hq[2] = (_Float16)(a0.z * L2E); hq[3] = (_Float16)(a0.w * L2E);
    hq[4] = (_Float16)(a1.x * L2E); hq[5] = (_Float16)(a1.y * L2E);
    hq[6] = (_Float16)(a1.z * L2E); hq[7] = (_Float16)(a1.w * L2E);
    qf[kc] = hq;
  }

  f32x4 o[4];                  // O^T frags: d = nf2*16+quad*4+r, q = col
#pragma unroll
  for (int nf = 0; nf < 4; ++nf) o[nf] = (f32x4){0.f, 0.f, 0.f, 0.f};
  float m_r = -1e30f, l_r = 0.f;

  // prologue: stage tile 0 into buf 0 (fp32 load -> cvt -> LDS)
  {
    const float* src = gV + (size_t)(kv0 + sr) * DH + sdc;
    float4 f[4] = {((const float4*)src)[0], ((const float4*)src)[1],
                   ((const float4*)src)[2], ((const float4*)src)[3]};
    stage_write(&lds[0][0][0], &lds[0][1][0], f);
  }

  int nIter = kvLen >> 6;
  int cur = 0;
  for (int it = 0; it < nIter; ++it) {
    __syncthreads();           // buf(cur) staged; buf(cur^1) free

    // issue next-tile fp32 loads NOW; body hides latency (16 held regs,
    // live total ~60 << the (256,4) 128-reg cap: no R7-style spill)
    float4 f[4];
    bool more = (it + 1) < nIter;
    if (more) {
      const float* src = gV + (size_t)(kv0 + ((it + 1) << 6) + sr) * DH + sdc;
      f[0] = ((const float4*)src)[0];
      f[1] = ((const float4*)src)[1];
      f[2] = ((const float4*)src)[2];
      f[3] = ((const float4*)src)[3];
    }

    const u16* sv = &lds[cur][0][0];
    const u16* st = &lds[cur][1][0];

    // ---- S^T = V @ Q^T : sf[nf] covers kv = nf*16 + quad*4 + r
    f32x4 sf[4];
#pragma unroll
    for (int nf = 0; nf < 4; ++nf) sf[nf] = (f32x4){0.f, 0.f, 0.f, 0.f};
#pragma unroll
    for (int nf = 0; nf < 4; ++nf) {
#pragma unroll
      for (int kc = 0; kc < 2; ++kc) {
        int ch = ((kc << 2) | quad) ^ c7;
        half8 av = *(const half8*)(sv + ((nf * 16 + col) << 6) + (ch << 3));
        sf[nf] = MFMA32(av, qf[kc], sf[nf]);
      }
    }

    // ---- online softmax (per-lane scalar state) -> P^T B-frags
    half4 pf[4];
    {
      float tm = sf[0][0];
#pragma unroll
      for (int nf = 0; nf < 4; ++nf)
#pragma unroll
        for (int r = 0; r < 4; ++r) tm = fmaxf(tm, sf[nf][r]);
      tm = fmaxf(tm, __shfl_xor(tm, 16, 64));
      tm = fmaxf(tm, __shfl_xor(tm, 32, 64));
      float mn = fmaxf(m_r, tm);
      float al = exp2f(m_r - mn);
      m_r = mn;
      float rs = 0.f;
#pragma unroll
      for (int nf = 0; nf < 4; ++nf) {
        float p0 = exp2f(sf[nf][0] - mn);
        float p1 = exp2f(sf[nf][1] - mn);
        float p2 = exp2f(sf[nf][2] - mn);
        float p3 = exp2f(sf[nf][3] - mn);
        rs += (p0 + p1) + (p2 + p3);
        half2v lo = pkrtz(p0, p1);
        half2v hi = pkrtz(p2, p3);
        pf[nf] = __builtin_shufflevector(lo, hi, 0, 1, 2, 3);
      }
      l_r = l_r * al + rs;
#pragma unroll
      for (int nf = 0; nf < 4; ++nf)
#pragma unroll
        for (int r = 0; r < 4; ++r) o[nf][r] *= al;
    }

    // ---- O^T += V^T @ P^T : one b128 feeds TWO K=16 MFMAs (kv-permute)
#pragma unroll
    for (int kc2 = 0; kc2 < 2; ++kc2) {
#pragma unroll
      for (int nf2 = 0; nf2 < 4; ++nf2) {
        int ch = ((kc2 << 2) | quad) ^ c7;
        half8 w8 = *(const half8*)(st + ((nf2 * 16 + col) << 6) + (ch << 3));
        half4 wlo = __builtin_shufflevector(w8, w8, 0, 1, 2, 3);
        half4 whi = __builtin_shufflevector(w8, w8, 4, 5, 6, 7);
        o[nf2] = MFMA16(wlo, pf[kc2 * 2], o[nf2]);
        o[nf2] = MFMA16(whi, pf[kc2 * 2 + 1], o[nf2]);
      }
    }

    // ---- convert + write staged tile -> other buffer (loads landed)
    if (more) stage_write(&lds[cur ^ 1][0][0], &lds[cur ^ 1][1][0], f);
    cur ^= 1;
  }

  // ---- epilogue: l reduce across quads, pm/pl, transpose O^T -> po[q][d]
  l_r += __shfl_xor(l_r, 16, 64);
  l_r += __shfl_xor(l_r, 32, 64);
  int pidx = tile * S + s;
  if (quad == 0) {
    pm[(size_t)pidx * 64 + (wave << 4) + col] = m_r;
    pl[(size_t)pidx * 64 + (wave << 4) + col] = l_r;
  }

  __syncthreads();             // tile buffers free; reuse as [64 q][72]
  u16* tp = &lds[0][0][0];
  {
    int qrow = (wave << 4) + col;
#pragma unroll
    for (int nf2 = 0; nf2 < 4; ++nf2) {
#pragma unroll
      for (int r2 = 0; r2 < 4; r2 += 2) {
        unsigned pk = (unsigned)f2h(o[nf2][r2]) |
                      ((unsigned)f2h(o[nf2][r2 + 1]) << 16);
        int d = nf2 * 16 + (quad << 2) + r2;
        *(unsigned*)(tp + qrow * 72 + d) = pk;
      }
    }
  }
  __syncthreads();
  {
    u16* pob = po + (size_t)pidx * 64 * 64;
    int q = t >> 2, hc = (t & 3) << 4;
    uint4 x0 = *(const uint4*)(tp + q * 72 + hc);
    uint4 x1 = *(const uint4*)(tp + q * 72 + hc + 8);
    *(uint4*)(pob + q * 64 + hc)     = x0;
    *(uint4*)(pob + q * 64 + hc + 8) = x1;
  }
}

// ------------------------------------------------------------- combine ----
// grid NB*SQ/32 blocks, 256 threads; thread = (q row, 8-d chunk).
__global__ __launch_bounds__(256) void combine_kernel(
    const u16* __restrict__ po,
    const float* __restrict__ pm,
    const float* __restrict__ pl,
    float* __restrict__ out, int S) {
  int t    = threadIdx.x;
  int rowg = blockIdx.x * 32 + (t >> 3);   // global q row
  int tile = rowg >> 6;
  int row  = rowg & 63;
  int dc   = (t & 7) << 3;

  float mv[8], lv[8];
  float M = -1e30f;
  for (int s = 0; s < S; ++s) {
    mv[s] = pm[(size_t)(tile * S + s) * 64 + row];
    lv[s] = pl[(size_t)(tile * S + s) * 64 + row];
    M = fmaxf(M, mv[s]);
  }
  float L = 0.f, w[8];
  for (int s = 0; s < S; ++s) {
    w[s] = exp2f(mv[s] - M);
    L += lv[s] * w[s];
  }
  float acc[8] = {0.f, 0.f, 0.f, 0.f, 0.f, 0.f, 0.f, 0.f};
  for (int s = 0; s < S; ++s) {
    const u16* p = po + (size_t)(tile * S + s) * 4096 + row * 64 + dc;
    uint4 raw = *(const uint4*)p;
    half8 x = __builtin_bit_cast(half8, raw);
#pragma unroll
    for (int k = 0; k < 8; ++k) acc[k] += w[s] * (float)x[k];
  }
  float invL = 1.0f / L;
  float* op = out + (size_t)rowg * 64 + dc;
  f32x4 o0 = (f32x4){acc[0], acc[1], acc[2], acc[3]};
  f32x4 o1 = (f32x4){acc[4], acc[5], acc[6], acc[7]};
  *(f32x4*)op       = o0 * invL;
  *(f32x4*)(op + 4) = o1 * invL;
}

// -------------------------------------------------------------- launch ----
extern "C" void kernel_launch(void* const* d_in, const int* in_sizes, int n_in,
                              void* d_out, int out_size, void* d_ws, size_t ws_size,
                              hipStream_t stream) {
  const float* Q = (const float*)d_in[0];
  const float* V = (const float*)d_in[1];
  float* out = (float*)d_out;

  auto partBytes = [](int S) {
    return (size_t)NB * 64 * S * ((size_t)64 * 64 * 2 + 64 * 8);
  };
  int S = 4;
  while (S > 1 && ws_size < partBytes(S)) S >>= 1;
  int kvLen = SKV / S;

  u16* po = (u16*)d_ws;
  float* pm = (float*)(po + (size_t)NB * 64 * S * 64 * 64);
  float* pl = pm + (size_t)NB * 64 * S * 64;

  attn_kernel<<<NB * 64 * S, 256, 0, stream>>>(Q, V, po, pm, pl, S, kvLen);
  combine_kernel<<<NB * SQ / 32, 256, 0, stream>>>(po, pm, pl, out, S);
}